// Round 15
// baseline (364.498 us; speedup 1.0000x reference)
//
#include <hip/hip_runtime.h>
#include <math.h>

// PixelQueryNet v15 = v14 (252us) + WB-read bank fix + 2-group gather lookahead.
// Per low-res cell (b,i,j): MLP 4->64->64->64->64->3 (leaky 0.01, tanh) on the
// 64 pixels of its 8x8 tile; weights from lr_params[b,c,i,j] (stride 4096 fl).
//
// Block = 256 thr = 4 cells(j) x 8 px-rows(pg) x 8 co-blocks(cob); y[8co][8px]
// in registers. A = two unpadded k-planes (lane-contiguous b128, conflict-free).
// Grid 2048; siblings n,n+8,n+16,n+24 (same XCD) take the four 16B j-quads of
// each 64B weight line -> FETCH ideal. 24 groups of 4 tiles, 2 barriers/group.
//
// v15 changes vs v14 (attacking the measured residuals):
//  * WROW 160 -> 164. At 160, WB-read quad starts within a wave are
//    j*160+cob*8 == {0,8} mod 32 (j*160==0!) -> 8 addresses on 2 bank-quads
//    = 4-way conflict (the surviving 1.26e7 counter). At 164: starts ==
//    4j+8cob -> {0,4,8,8,12,12,16,20} -> <=2-way = free.
//  * Gather lookahead 2 groups: pairs P0/P1 rotated by parity; gather for
//    g+3 issued at end of iter g, consumed (WB write) at end of iter g+2
//    -> ~2 group-slots of flight for the 64-line gathers. +8 VGPR (~112<128).
// R9-R13 lesson: keep register state small; never exceed the 128-VGPR target.

static constexpr int PLANE = 4096;
static constexpr int NPAR  = 12995;
static constexpr int WROW  = 164;   // 164%32=4, 164%4=0: read starts 4j+8cob
static constexpr int AHI   = 8192;  // word offset of k4..7 plane

__device__ __forceinline__ float leaky(float v) { return fmaxf(v, 0.01f * v); }

// PE x-features, compile-time: cos/sin(2*pi*k/8), k = dx.
__device__ __forceinline__ constexpr float cx(int k) {
  constexpr float R = 0.70710678118654752f;
  const float t[8] = {1.f, R, 0.f, -R, -1.f, -R, 0.f, R};
  return t[k];
}
__device__ __forceinline__ constexpr float sx(int k) {
  constexpr float R = 0.70710678118654752f;
  const float t[8] = {0.f, R, 1.f, R, 0.f, -R, -1.f, -R};
  return t[k];
}

__global__ __launch_bounds__(256, 1) void pqn(const float* __restrict__ lr,
                                              float* __restrict__ out) {
  __shared__ alignas(16) float A[2 * AHI];        // 65536 B activations
  __shared__ alignas(16) float WB[4][4 * WROW];   // 10496 B weight quad-buffer

  const int tid = threadIdx.x;
  const int j   = tid & 3;
  const int pg  = (tid >> 2) & 7;      // pixel row (dy)
  const int cob = tid >> 5;            // 0..7

  // ---- swizzle: 4 siblings (same XCD) cover one 64B weight line
  const int n  = blockIdx.x;
  const int e2 = (n >> 3) & 3;
  const int P  = (n & 7) | ((n >> 5) << 3);   // 0..511
  const int jg = ((P & 3) << 2) | e2;         // 0..15
  const int i  = (P >> 2) & 63;
  const int b  = (P >> 8) & 1;

  const float* __restrict__ wb =
      lr + (size_t)b * NPAR * PLANE + (size_t)(i * 64 + jg * 4);
  const float* __restrict__ pt = wb + j;      // per-thread channel base

  float fyc, fys;
  sincosf(0.78539816339744830962f * pg, &fys, &fyc);

  const int abase = pg * 16 + j * 4;   // lane-contiguous A offset
  const int wrow  = j * WROW;
  const int sq    = tid >> 7;          // staging: which tile-pair half
  const int sc    = tid & 127;         // staging channel within tile

  auto gaddr = [&](int g) -> size_t {  // first channel of group g's weights
    return 384 + (size_t)(g >> 3) * 4160 + (size_t)(g & 7) * 512;
  };

  // ---- prologue: group-0 gather -> WB; then preload g1 (P0) and g2 (P1)
  float4 pA0, pB0, pA1, pB1;
  {
    const size_t cb = gaddr(0);
    pA0 = *(const float4*)(wb + (cb + tid) * PLANE);
    pB0 = *(const float4*)(wb + (cb + 256 + tid) * PLANE);
  }
  float l0b[8], l0w[32], bb[8];
#pragma unroll
  for (int m = 0; m < 8; ++m) l0b[m] = pt[(size_t)(cob * 8 + m) * PLANE];
#pragma unroll
  for (int f = 0; f < 4; ++f)
#pragma unroll
    for (int m = 0; m < 8; ++m)
      l0w[f * 8 + m] = pt[(size_t)(64 + f * 64 + cob * 8 + m) * PLANE];
#pragma unroll
  for (int m = 0; m < 8; ++m) bb[m] = pt[(size_t)(320 + cob * 8 + m) * PLANE];

  // ---- L0 compute -> A
#pragma unroll
  for (int col = 0; col < 8; ++col) {
    float t[8];
#pragma unroll
    for (int k = 0; k < 8; ++k) {
      float v = l0b[col];
      v = fmaf(cx(k), l0w[col], v);
      v = fmaf(sx(k), l0w[8 + col], v);
      v = fmaf(fyc,  l0w[16 + col], v);
      v = fmaf(fys,  l0w[24 + col], v);
      t[k] = leaky(v);
    }
    float4 v0, v1;
    v0.x = t[0]; v0.y = t[1]; v0.z = t[2]; v0.w = t[3];
    v1.x = t[4]; v1.y = t[5]; v1.z = t[6]; v1.w = t[7];
    *(float4*)&A[(cob * 8 + col) * 128 + abase]       = v0;
    *(float4*)&A[(cob * 8 + col) * 128 + abase + AHI] = v1;
  }
  // stage group-0 weights into WB, then issue g1/g2 gathers
#pragma unroll
  for (int jj = 0; jj < 4; ++jj) {
    WB[sq][jj * WROW + sc]     = ((const float*)&pA0)[jj];
    WB[2 + sq][jj * WROW + sc] = ((const float*)&pB0)[jj];
  }
  {
    size_t cb = gaddr(1);
    pA0 = *(const float4*)(wb + (cb + tid) * PLANE);
    pB0 = *(const float4*)(wb + (cb + 256 + tid) * PLANE);
    cb = gaddr(2);
    pA1 = *(const float4*)(wb + (cb + tid) * PLANE);
    pB1 = *(const float4*)(wb + (cb + 256 + tid) * PLANE);
  }
  asm volatile("s_waitcnt lgkmcnt(0)" ::: "memory");
  __builtin_amdgcn_s_barrier();
  __builtin_amdgcn_sched_barrier(0);

  float y[64];
#pragma unroll
  for (int m = 0; m < 64; ++m) y[m] = 0.f;

  // ---- 24 groups of 4 tiles (8 ci); invariant at loop top:
  //   WB = group g; P[g&1] = group g+1; P[(g+1)&1] = group g+2 (in flight)
#pragma unroll 1
  for (int g = 0; g < 24; ++g) {
    // compute 4 tiles from WB[0..3]
    const int r0 = (g & 7) * 8;          // ci base of this group
#pragma unroll
    for (int q = 0; q < 4; ++q) {
      const float* Wt = WB[q];
#pragma unroll
      for (int cl = 0; cl < 2; ++cl) {
        const int ci = r0 + q * 2 + cl;
        const float4 a0 = *(const float4*)&A[ci * 128 + abase];
        const float4 a1 = *(const float4*)&A[ci * 128 + abase + AHI];
        const float4 w0 = *(const float4*)&Wt[wrow + cl * 64 + cob * 8];
        const float4 w1 = *(const float4*)&Wt[wrow + cl * 64 + cob * 8 + 4];
        const float av[8] = {a0.x, a0.y, a0.z, a0.w, a1.x, a1.y, a1.z, a1.w};
        const float wv[8] = {w0.x, w0.y, w0.z, w0.w, w1.x, w1.y, w1.z, w1.w};
#pragma unroll
        for (int col = 0; col < 8; ++col)
#pragma unroll
          for (int k = 0; k < 8; ++k)
            y[col * 8 + k] = fmaf(av[k], wv[col], y[col * 8 + k]);
      }
    }
    asm volatile("s_waitcnt lgkmcnt(0)" ::: "memory");
    __builtin_amdgcn_s_barrier();        // everyone's A/WB reads done
    __builtin_amdgcn_sched_barrier(0);

    if ((g & 7) == 7) {                  // layer end: bias + leaky -> A
      const int l = g >> 3;
#pragma unroll
      for (int col = 0; col < 8; ++col) {
        float4 v0, v1;
        v0.x = leaky(y[col * 8 + 0] + bb[col]);
        v0.y = leaky(y[col * 8 + 1] + bb[col]);
        v0.z = leaky(y[col * 8 + 2] + bb[col]);
        v0.w = leaky(y[col * 8 + 3] + bb[col]);
        v1.x = leaky(y[col * 8 + 4] + bb[col]);
        v1.y = leaky(y[col * 8 + 5] + bb[col]);
        v1.z = leaky(y[col * 8 + 6] + bb[col]);
        v1.w = leaky(y[col * 8 + 7] + bb[col]);
        *(float4*)&A[(cob * 8 + col) * 128 + abase]       = v0;
        *(float4*)&A[(cob * 8 + col) * 128 + abase + AHI] = v1;
      }
#pragma unroll
      for (int m = 0; m < 64; ++m) y[m] = 0.f;
      if (l < 2) {
#pragma unroll
        for (int m = 0; m < 8; ++m)
          bb[m] = pt[(size_t)(320 + (l + 1) * 4160 + cob * 8 + m) * PLANE];
      }
    }
    if (g + 1 < 24) {                    // publish group g+1 from P[g&1]
      const float4& wA = (g & 1) ? pA1 : pA0;
      const float4& wB = (g & 1) ? pB1 : pB0;
#pragma unroll
      for (int jj = 0; jj < 4; ++jj) {
        WB[sq][jj * WROW + sc]     = ((const float*)&wA)[jj];
        WB[2 + sq][jj * WROW + sc] = ((const float*)&wB)[jj];
      }
    }
    if (g + 3 < 24) {                    // refill P[g&1] with group g+3
      const size_t cb = gaddr(g + 3);
      float4& wA = (g & 1) ? pA1 : pA0;
      float4& wB = (g & 1) ? pB1 : pB0;
      wA = *(const float4*)(wb + (cb + tid) * PLANE);
      wB = *(const float4*)(wb + (cb + 256 + tid) * PLANE);
    }
    asm volatile("s_waitcnt lgkmcnt(0)" ::: "memory");
    __builtin_amdgcn_s_barrier();        // A-flush + WB writes visible
    __builtin_amdgcn_sched_barrier(0);
  }

  // ---- epilogue: L4 (64 -> 3) + tanh
  float po[24];
#pragma unroll
  for (int m = 0; m < 24; ++m) po[m] = 0.f;
#pragma unroll
  for (int cl = 0; cl < 8; ++cl) {
    const int ci = cob * 8 + cl;
    const float4 a0 = *(const float4*)&A[ci * 128 + abase];
    const float4 a1 = *(const float4*)&A[ci * 128 + abase + AHI];
#pragma unroll
    for (int o = 0; o < 3; ++o) {
      const float w = pt[(size_t)(12803 + ci * 3 + o) * PLANE];
      po[o * 8 + 0] = fmaf(a0.x, w, po[o * 8 + 0]);
      po[o * 8 + 1] = fmaf(a0.y, w, po[o * 8 + 1]);
      po[o * 8 + 2] = fmaf(a0.z, w, po[o * 8 + 2]);
      po[o * 8 + 3] = fmaf(a0.w, w, po[o * 8 + 3]);
      po[o * 8 + 4] = fmaf(a1.x, w, po[o * 8 + 4]);
      po[o * 8 + 5] = fmaf(a1.y, w, po[o * 8 + 5]);
      po[o * 8 + 6] = fmaf(a1.z, w, po[o * 8 + 6]);
      po[o * 8 + 7] = fmaf(a1.w, w, po[o * 8 + 7]);
    }
  }
  asm volatile("s_waitcnt lgkmcnt(0)" ::: "memory");
  __builtin_amdgcn_s_barrier();        // all A reads done -> reuse A
  float* R = A;
#pragma unroll
  for (int m = 0; m < 24; m += 4)
    *(float4*)&R[tid * 28 + m] = *(float4*)&po[m];
  asm volatile("s_waitcnt lgkmcnt(0)" ::: "memory");
  __builtin_amdgcn_s_barrier();
  __builtin_amdgcn_sched_barrier(0);

  if (cob == 0) {                      // tid < 32: one (j, pg) per thread
#pragma unroll
    for (int o = 0; o < 3; ++o) {
      const float bias = pt[(size_t)(12800 + o) * PLANE];
      float s[8];
#pragma unroll
      for (int k = 0; k < 8; ++k) s[k] = bias;
#pragma unroll
      for (int cb = 0; cb < 8; ++cb) {
#pragma unroll
        for (int k = 0; k < 8; ++k)
          s[k] += R[(cb * 32 + tid) * 28 + o * 8 + k];
      }
      float4 v0, v1;
      v0.x = tanhf(s[0]); v0.y = tanhf(s[1]); v0.z = tanhf(s[2]); v0.w = tanhf(s[3]);
      v1.x = tanhf(s[4]); v1.y = tanhf(s[5]); v1.z = tanhf(s[6]); v1.w = tanhf(s[7]);
      float* op = out + (size_t)b * 786432 + (size_t)o * 262144 +
                  (size_t)(i * 8 + pg) * 512 + (size_t)((jg * 4 + j) * 8);
      *(float4*)op = v0;
      *(float4*)(op + 4) = v1;
    }
  }
}

extern "C" void kernel_launch(void* const* d_in, const int* in_sizes, int n_in,
                              void* d_out, int out_size, void* d_ws, size_t ws_size,
                              hipStream_t stream) {
  (void)in_sizes; (void)n_in; (void)d_ws; (void)ws_size; (void)out_size;
  const float* lr = (const float*)d_in[1];  // d_in[0] = highres (unused by the math)
  float* out = (float*)d_out;
  hipLaunchKernelGGL(pqn, dim3(2048), dim3(256), 0, stream, lr, out);
}

// Round 16
// 250.839 us; speedup vs baseline: 1.4531x; 1.4531x over previous
//
#include <hip/hip_runtime.h>
#include <math.h>

// PixelQueryNet v16 = v14 (252us) + WROW=164 bank fix (proven R15: conflicts
// -> 0) + 2-group gather lookahead with STATIC parity (manual unroll-by-2).
// R15 lesson (= rule #20): runtime-parity register selects ((g&1)? pA1 : pA0)
// demote staging regs to scratch (277 MB writes, -45%). Parity must be static.
//
// Per low-res cell (b,i,j): MLP 4->64->64->64->64->3 (leaky 0.01, tanh) on the
// 64 pixels of its 8x8 tile; weights from lr_params[b,c,i,j] (stride 4096 fl).
//
// Block = 256 thr = 4 cells(j) x 8 px-rows(pg) x 8 co-blocks(cob); y[8co][8px]
// in registers. A = two unpadded k-planes (lane-contiguous b128, conflict-free).
// Grid 2048; siblings n,n+8,n+16,n+24 (same XCD) take the four 16B j-quads of
// each 64B weight line -> FETCH ideal. 24 groups of 4 tiles, 2 barriers/group;
// gathers for group g+3 issued at end of group g (2 slots of flight), consumed
// by the WB publish at end of group g+2. Pa serves odd publishes, Pb even.

static constexpr int PLANE = 4096;
static constexpr int NPAR  = 12995;
static constexpr int WROW  = 164;   // read quad starts 4j+8cob mod 32: <=2-way
static constexpr int AHI   = 8192;  // word offset of k4..7 plane

__device__ __forceinline__ float leaky(float v) { return fmaxf(v, 0.01f * v); }

// PE x-features, compile-time: cos/sin(2*pi*k/8), k = dx.
__device__ __forceinline__ constexpr float cx(int k) {
  constexpr float R = 0.70710678118654752f;
  const float t[8] = {1.f, R, 0.f, -R, -1.f, -R, 0.f, R};
  return t[k];
}
__device__ __forceinline__ constexpr float sx(int k) {
  constexpr float R = 0.70710678118654752f;
  const float t[8] = {0.f, R, 1.f, R, 0.f, -R, -1.f, -R};
  return t[k];
}

__global__ __launch_bounds__(256, 1) void pqn(const float* __restrict__ lr,
                                              float* __restrict__ out) {
  __shared__ alignas(16) float A[2 * AHI];        // 65536 B activations
  __shared__ alignas(16) float WB[4][4 * WROW];   // 10496 B weight quad-buffer

  const int tid = threadIdx.x;
  const int j   = tid & 3;
  const int pg  = (tid >> 2) & 7;      // pixel row (dy)
  const int cob = tid >> 5;            // 0..7

  // ---- swizzle: 4 siblings (same XCD) cover one 64B weight line
  const int n  = blockIdx.x;
  const int e2 = (n >> 3) & 3;
  const int P  = (n & 7) | ((n >> 5) << 3);   // 0..511
  const int jg = ((P & 3) << 2) | e2;         // 0..15
  const int i  = (P >> 2) & 63;
  const int b  = (P >> 8) & 1;

  const float* __restrict__ wb =
      lr + (size_t)b * NPAR * PLANE + (size_t)(i * 64 + jg * 4);
  const float* __restrict__ pt = wb + j;      // per-thread channel base

  float fyc, fys;
  sincosf(0.78539816339744830962f * pg, &fys, &fyc);

  const int abase = pg * 16 + j * 4;   // lane-contiguous A offset
  const int wrow  = j * WROW;
  const int sq    = tid >> 7;          // staging: which tile-pair half
  const int sc    = tid & 127;         // staging channel within tile

  auto gaddr = [&](int g) -> size_t {  // first channel of group g's weights
    return 384 + (size_t)(g >> 3) * 4160 + (size_t)(g & 7) * 512;
  };

  float4 paA, paB, pbA, pbB;           // static staging pairs (odd / even)
  {
    const size_t cb = gaddr(0);
    paA = *(const float4*)(wb + (cb + tid) * PLANE);
    paB = *(const float4*)(wb + (cb + 256 + tid) * PLANE);
  }
  float l0b[8], l0w[32], bb[8];
#pragma unroll
  for (int m = 0; m < 8; ++m) l0b[m] = pt[(size_t)(cob * 8 + m) * PLANE];
#pragma unroll
  for (int f = 0; f < 4; ++f)
#pragma unroll
    for (int m = 0; m < 8; ++m)
      l0w[f * 8 + m] = pt[(size_t)(64 + f * 64 + cob * 8 + m) * PLANE];
#pragma unroll
  for (int m = 0; m < 8; ++m) bb[m] = pt[(size_t)(320 + cob * 8 + m) * PLANE];

  // ---- L0 compute -> A
#pragma unroll
  for (int col = 0; col < 8; ++col) {
    float t[8];
#pragma unroll
    for (int k = 0; k < 8; ++k) {
      float v = l0b[col];
      v = fmaf(cx(k), l0w[col], v);
      v = fmaf(sx(k), l0w[8 + col], v);
      v = fmaf(fyc,  l0w[16 + col], v);
      v = fmaf(fys,  l0w[24 + col], v);
      t[k] = leaky(v);
    }
    float4 v0, v1;
    v0.x = t[0]; v0.y = t[1]; v0.z = t[2]; v0.w = t[3];
    v1.x = t[4]; v1.y = t[5]; v1.z = t[6]; v1.w = t[7];
    *(float4*)&A[(cob * 8 + col) * 128 + abase]       = v0;
    *(float4*)&A[(cob * 8 + col) * 128 + abase + AHI] = v1;
  }
  // publish group 0, then preload: Pa <- g1 (odd publishes), Pb <- g2 (even)
#pragma unroll
  for (int jj = 0; jj < 4; ++jj) {
    WB[sq][jj * WROW + sc]     = ((const float*)&paA)[jj];
    WB[2 + sq][jj * WROW + sc] = ((const float*)&paB)[jj];
  }
  {
    size_t cb = gaddr(1);
    paA = *(const float4*)(wb + (cb + tid) * PLANE);
    paB = *(const float4*)(wb + (cb + 256 + tid) * PLANE);
    cb = gaddr(2);
    pbA = *(const float4*)(wb + (cb + tid) * PLANE);
    pbB = *(const float4*)(wb + (cb + 256 + tid) * PLANE);
  }
  asm volatile("s_waitcnt lgkmcnt(0)" ::: "memory");
  __builtin_amdgcn_s_barrier();
  __builtin_amdgcn_sched_barrier(0);

  float y[64];
#pragma unroll
  for (int m = 0; m < 64; ++m) y[m] = 0.f;

  // compute one group's 4 tiles out of WB
  auto cgrp = [&](int g) {
    const int r0 = (g & 7) * 8;
#pragma unroll
    for (int q = 0; q < 4; ++q) {
      const float* Wt = WB[q];
#pragma unroll
      for (int cl = 0; cl < 2; ++cl) {
        const int ci = r0 + q * 2 + cl;
        const float4 a0 = *(const float4*)&A[ci * 128 + abase];
        const float4 a1 = *(const float4*)&A[ci * 128 + abase + AHI];
        const float4 w0 = *(const float4*)&Wt[wrow + cl * 64 + cob * 8];
        const float4 w1 = *(const float4*)&Wt[wrow + cl * 64 + cob * 8 + 4];
        const float av[8] = {a0.x, a0.y, a0.z, a0.w, a1.x, a1.y, a1.z, a1.w};
        const float wv[8] = {w0.x, w0.y, w0.z, w0.w, w1.x, w1.y, w1.z, w1.w};
#pragma unroll
        for (int col = 0; col < 8; ++col)
#pragma unroll
          for (int k = 0; k < 8; ++k)
            y[col * 8 + k] = fmaf(av[k], wv[col], y[col * 8 + k]);
      }
    }
    asm volatile("s_waitcnt lgkmcnt(0)" ::: "memory");
    __builtin_amdgcn_s_barrier();        // everyone's A/WB reads done
    __builtin_amdgcn_sched_barrier(0);
  };
  auto flush = [&](int l) {              // layer end: bias + leaky -> A
#pragma unroll
    for (int col = 0; col < 8; ++col) {
      float4 v0, v1;
      v0.x = leaky(y[col * 8 + 0] + bb[col]);
      v0.y = leaky(y[col * 8 + 1] + bb[col]);
      v0.z = leaky(y[col * 8 + 2] + bb[col]);
      v0.w = leaky(y[col * 8 + 3] + bb[col]);
      v1.x = leaky(y[col * 8 + 4] + bb[col]);
      v1.y = leaky(y[col * 8 + 5] + bb[col]);
      v1.z = leaky(y[col * 8 + 6] + bb[col]);
      v1.w = leaky(y[col * 8 + 7] + bb[col]);
      *(float4*)&A[(cob * 8 + col) * 128 + abase]       = v0;
      *(float4*)&A[(cob * 8 + col) * 128 + abase + AHI] = v1;
    }
#pragma unroll
    for (int m = 0; m < 64; ++m) y[m] = 0.f;
    if (l < 2) {
#pragma unroll
      for (int m = 0; m < 8; ++m)
        bb[m] = pt[(size_t)(320 + (l + 1) * 4160 + cob * 8 + m) * PLANE];
    }
  };

  // ---- 12 super-iterations of 2 groups; parity of Pa/Pb is STATIC
#pragma unroll 1
  for (int u = 0; u < 12; ++u) {
    const int g0 = u * 2;                // even group
    // -------- even group g0: publish g0+1 from Pa, refill Pa with g0+3
    cgrp(g0);
#pragma unroll
    for (int jj = 0; jj < 4; ++jj) {
      WB[sq][jj * WROW + sc]     = ((const float*)&paA)[jj];
      WB[2 + sq][jj * WROW + sc] = ((const float*)&paB)[jj];
    }
    if (g0 + 3 < 24) {
      const size_t cb = gaddr(g0 + 3);
      paA = *(const float4*)(wb + (cb + tid) * PLANE);
      paB = *(const float4*)(wb + (cb + 256 + tid) * PLANE);
    }
    asm volatile("s_waitcnt lgkmcnt(0)" ::: "memory");
    __builtin_amdgcn_s_barrier();
    __builtin_amdgcn_sched_barrier(0);

    // -------- odd group g1 = g0+1: flush at layer ends (g1 = 7,15,23)
    const int g1 = g0 + 1;
    cgrp(g1);
    if ((g1 & 7) == 7) flush(g1 >> 3);
    if (g1 + 1 < 24) {
#pragma unroll
      for (int jj = 0; jj < 4; ++jj) {
        WB[sq][jj * WROW + sc]     = ((const float*)&pbA)[jj];
        WB[2 + sq][jj * WROW + sc] = ((const float*)&pbB)[jj];
      }
    }
    if (g1 + 3 < 24) {
      const size_t cb = gaddr(g1 + 3);
      pbA = *(const float4*)(wb + (cb + tid) * PLANE);
      pbB = *(const float4*)(wb + (cb + 256 + tid) * PLANE);
    }
    asm volatile("s_waitcnt lgkmcnt(0)" ::: "memory");
    __builtin_amdgcn_s_barrier();
    __builtin_amdgcn_sched_barrier(0);
  }

  // ---- epilogue: L4 (64 -> 3) + tanh
  float po[24];
#pragma unroll
  for (int m = 0; m < 24; ++m) po[m] = 0.f;
#pragma unroll
  for (int cl = 0; cl < 8; ++cl) {
    const int ci = cob * 8 + cl;
    const float4 a0 = *(const float4*)&A[ci * 128 + abase];
    const float4 a1 = *(const float4*)&A[ci * 128 + abase + AHI];
#pragma unroll
    for (int o = 0; o < 3; ++o) {
      const float w = pt[(size_t)(12803 + ci * 3 + o) * PLANE];
      po[o * 8 + 0] = fmaf(a0.x, w, po[o * 8 + 0]);
      po[o * 8 + 1] = fmaf(a0.y, w, po[o * 8 + 1]);
      po[o * 8 + 2] = fmaf(a0.z, w, po[o * 8 + 2]);
      po[o * 8 + 3] = fmaf(a0.w, w, po[o * 8 + 3]);
      po[o * 8 + 4] = fmaf(a1.x, w, po[o * 8 + 4]);
      po[o * 8 + 5] = fmaf(a1.y, w, po[o * 8 + 5]);
      po[o * 8 + 6] = fmaf(a1.z, w, po[o * 8 + 6]);
      po[o * 8 + 7] = fmaf(a1.w, w, po[o * 8 + 7]);
    }
  }
  asm volatile("s_waitcnt lgkmcnt(0)" ::: "memory");
  __builtin_amdgcn_s_barrier();        // all A reads done -> reuse A
  float* R = A;
#pragma unroll
  for (int m = 0; m < 24; m += 4)
    *(float4*)&R[tid * 28 + m] = *(float4*)&po[m];
  asm volatile("s_waitcnt lgkmcnt(0)" ::: "memory");
  __builtin_amdgcn_s_barrier();
  __builtin_amdgcn_sched_barrier(0);

  if (cob == 0) {                      // tid < 32: one (j, pg) per thread
#pragma unroll
    for (int o = 0; o < 3; ++o) {
      const float bias = pt[(size_t)(12800 + o) * PLANE];
      float s[8];
#pragma unroll
      for (int k = 0; k < 8; ++k) s[k] = bias;
#pragma unroll
      for (int cb = 0; cb < 8; ++cb) {
#pragma unroll
        for (int k = 0; k < 8; ++k)
          s[k] += R[(cb * 32 + tid) * 28 + o * 8 + k];
      }
      float4 v0, v1;
      v0.x = tanhf(s[0]); v0.y = tanhf(s[1]); v0.z = tanhf(s[2]); v0.w = tanhf(s[3]);
      v1.x = tanhf(s[4]); v1.y = tanhf(s[5]); v1.z = tanhf(s[6]); v1.w = tanhf(s[7]);
      float* op = out + (size_t)b * 786432 + (size_t)o * 262144 +
                  (size_t)(i * 8 + pg) * 512 + (size_t)((jg * 4 + j) * 8);
      *(float4*)op = v0;
      *(float4*)(op + 4) = v1;
    }
  }
}

extern "C" void kernel_launch(void* const* d_in, const int* in_sizes, int n_in,
                              void* d_out, int out_size, void* d_ws, size_t ws_size,
                              hipStream_t stream) {
  (void)in_sizes; (void)n_in; (void)d_ws; (void)ws_size; (void)out_size;
  const float* lr = (const float*)d_in[1];  // d_in[0] = highres (unused by the math)
  float* out = (float*)d_out;
  hipLaunchKernelGGL(pqn, dim3(2048), dim3(256), 0, stream, lr, out);
}

// Round 18
// 249.196 us; speedup vs baseline: 1.4627x; 1.0066x over previous
//
#include <hip/hip_runtime.h>
#include <math.h>

// PixelQueryNet v18 = v16 (250us) + true WB ring (2 groups) -> ONE barrier per
// group, XOR-swizzled 128-word weight rows so LDS = 64K(A) + 16K(WB) = 80KB
// exactly (2 blocks/CU preserved).
// R17 lesson: f16 activations FAIL accuracy (hidden acts reach O(1e3); abs err
// O(1) at tanh input). A stays fp32.
//
// Per low-res cell (b,i,j): MLP 4->64->64->64->64->3 (leaky 0.01, tanh) on the
// 64 pixels of its 8x8 tile; weights from lr_params[b,c,i,j] (stride 4096 fl).
//
// Block = 256 thr = 4 cells(j) x 8 px-rows(pg) x 8 co-blocks(cob); y[8co][8px]
// fp32 in registers. A = two unpadded fp32 k-planes (lane-contiguous b128,
// conflict-free, proven). Grid 2048; siblings n,n+8,n+16,n+24 (same XCD) take
// the four 16B j-quads of each 64B weight line -> FETCH ideal.
//
// Ring discipline: during group g, compute reads half g&1; publish(g+1) writes
// half (g+1)&1 (disjoint); ONE barrier at group end gives write-visibility for
// g+1 and read-completion for the half that g+2's publish will overwrite.
// Weight row swizzle: channel ch of row j lives at j*128 + (ch ^ (4*j));
// read-quad starts (8cob+{0,4})^4j -> <=2-way banks; b128 contiguity holds
// (XOR bits >=2, starts 4-aligned). Gathers: 2-group lookahead, STATIC parity
// (Pa even-publishes? Pa serves publishes at even groups, Pb at odd; refill
// g+3 at g). Flush (+1 barrier) at the 3 layer ends. ~30 barriers vs v16's 51.

static constexpr int PLANE = 4096;
static constexpr int NPAR  = 12995;
static constexpr int AHI   = 8192;  // word offset of k4..7 plane

__device__ __forceinline__ float leaky(float v) { return fmaxf(v, 0.01f * v); }

// PE x-features, compile-time: cos/sin(2*pi*k/8), k = dx.
__device__ __forceinline__ constexpr float cx(int k) {
  constexpr float R = 0.70710678118654752f;
  const float t[8] = {1.f, R, 0.f, -R, -1.f, -R, 0.f, R};
  return t[k];
}
__device__ __forceinline__ constexpr float sx(int k) {
  constexpr float R = 0.70710678118654752f;
  const float t[8] = {0.f, R, 1.f, R, 0.f, -R, -1.f, -R};
  return t[k];
}

__global__ __launch_bounds__(256, 1) void pqn(const float* __restrict__ lr,
                                              float* __restrict__ out) {
  __shared__ alignas(16) float A[2 * AHI];     // 65536 B activations (fp32)
  __shared__ alignas(16) float WB[2][2048];    // 16384 B ring: 2 halves x 4 tiles

  const int tid = threadIdx.x;
  const int j   = tid & 3;
  const int pg  = (tid >> 2) & 7;      // pixel row (dy)
  const int cob = tid >> 5;            // 0..7

  // ---- swizzle: 4 siblings (same XCD) cover one 64B weight line
  const int n  = blockIdx.x;
  const int e2 = (n >> 3) & 3;
  const int P  = (n & 7) | ((n >> 5) << 3);   // 0..511
  const int jg = ((P & 3) << 2) | e2;         // 0..15
  const int i  = (P >> 2) & 63;
  const int b  = (P >> 8) & 1;

  const float* __restrict__ wb =
      lr + (size_t)b * NPAR * PLANE + (size_t)(i * 64 + jg * 4);
  const float* __restrict__ pt = wb + j;      // per-thread channel base

  float fyc, fys;
  sincosf(0.78539816339744830962f * pg, &fys, &fyc);

  const int abase = pg * 16 + j * 4;   // lane-contiguous A offset
  const int swz   = j * 4;             // weight-row XOR swizzle
  const int wr0   = (cob * 8) ^ swz;   // cl=0 quad starts (w0, w1=+4^..)
  const int sq    = tid >> 7;          // staging: which tile-pair half
  const int sc    = tid & 127;         // staging channel within tile

  auto gaddr = [&](int g) -> size_t {  // first channel of group g's weights
    return 384 + (size_t)(g >> 3) * 4160 + (size_t)(g & 7) * 512;
  };

  float4 paA, paB, pbA, pbB;           // static staging pairs
  {
    const size_t cb = gaddr(0);
    paA = *(const float4*)(wb + (cb + tid) * PLANE);
    paB = *(const float4*)(wb + (cb + 256 + tid) * PLANE);
  }
  float l0b[8], l0w[32], bb[8];
#pragma unroll
  for (int m = 0; m < 8; ++m) l0b[m] = pt[(size_t)(cob * 8 + m) * PLANE];
#pragma unroll
  for (int f = 0; f < 4; ++f)
#pragma unroll
    for (int m = 0; m < 8; ++m)
      l0w[f * 8 + m] = pt[(size_t)(64 + f * 64 + cob * 8 + m) * PLANE];
#pragma unroll
  for (int m = 0; m < 8; ++m) bb[m] = pt[(size_t)(320 + cob * 8 + m) * PLANE];

  // ---- L0 compute -> A
#pragma unroll
  for (int col = 0; col < 8; ++col) {
    float t[8];
#pragma unroll
    for (int k = 0; k < 8; ++k) {
      float v = l0b[col];
      v = fmaf(cx(k), l0w[col], v);
      v = fmaf(sx(k), l0w[8 + col], v);
      v = fmaf(fyc,  l0w[16 + col], v);
      v = fmaf(fys,  l0w[24 + col], v);
      t[k] = leaky(v);
    }
    float4 v0, v1;
    v0.x = t[0]; v0.y = t[1]; v0.z = t[2]; v0.w = t[3];
    v1.x = t[4]; v1.y = t[5]; v1.z = t[6]; v1.w = t[7];
    *(float4*)&A[(cob * 8 + col) * 128 + abase]       = v0;
    *(float4*)&A[(cob * 8 + col) * 128 + abase + AHI] = v1;
  }
  // publish group 0 -> half 0; preload Pa <- g1, Pb <- g2
#pragma unroll
  for (int jj = 0; jj < 4; ++jj) {
    WB[0][sq * 512       + jj * 128 + (sc ^ (jj * 4))] = ((const float*)&paA)[jj];
    WB[0][(2 + sq) * 512 + jj * 128 + (sc ^ (jj * 4))] = ((const float*)&paB)[jj];
  }
  {
    size_t cb = gaddr(1);
    paA = *(const float4*)(wb + (cb + tid) * PLANE);
    paB = *(const float4*)(wb + (cb + 256 + tid) * PLANE);
    cb = gaddr(2);
    pbA = *(const float4*)(wb + (cb + tid) * PLANE);
    pbB = *(const float4*)(wb + (cb + 256 + tid) * PLANE);
  }
  asm volatile("s_waitcnt lgkmcnt(0)" ::: "memory");
  __builtin_amdgcn_s_barrier();
  __builtin_amdgcn_sched_barrier(0);

  float y[64];
#pragma unroll
  for (int m = 0; m < 64; ++m) y[m] = 0.f;

  // compute one group's 4 tiles out of ring half h (h literal at call sites)
  auto cgrp = [&](int g, int h) {
    const int r0 = (g & 7) * 8;
#pragma unroll
    for (int q = 0; q < 4; ++q) {
      const float* Wt = &WB[h][q * 512 + j * 128];
#pragma unroll
      for (int cl = 0; cl < 2; ++cl) {
        const int ci = r0 + q * 2 + cl;
        const float4 a0 = *(const float4*)&A[ci * 128 + abase];
        const float4 a1 = *(const float4*)&A[ci * 128 + abase + AHI];
        const float4 w0 = *(const float4*)&Wt[(cl * 64) + wr0];
        const float4 w1 = *(const float4*)&Wt[((cl * 64 + cob * 8 + 4) ^ swz)];
        const float av[8] = {a0.x, a0.y, a0.z, a0.w, a1.x, a1.y, a1.z, a1.w};
        const float wv[8] = {w0.x, w0.y, w0.z, w0.w, w1.x, w1.y, w1.z, w1.w};
#pragma unroll
        for (int col = 0; col < 8; ++col)
#pragma unroll
          for (int k = 0; k < 8; ++k)
            y[col * 8 + k] = fmaf(av[k], wv[col], y[col * 8 + k]);
      }
    }
  };
  auto flush = [&](int l) {              // layer end: bias + leaky -> A
#pragma unroll
    for (int col = 0; col < 8; ++col) {
      float4 v0, v1;
      v0.x = leaky(y[col * 8 + 0] + bb[col]);
      v0.y = leaky(y[col * 8 + 1] + bb[col]);
      v0.z = leaky(y[col * 8 + 2] + bb[col]);
      v0.w = leaky(y[col * 8 + 3] + bb[col]);
      v1.x = leaky(y[col * 8 + 4] + bb[col]);
      v1.y = leaky(y[col * 8 + 5] + bb[col]);
      v1.z = leaky(y[col * 8 + 6] + bb[col]);
      v1.w = leaky(y[col * 8 + 7] + bb[col]);
      *(float4*)&A[(cob * 8 + col) * 128 + abase]       = v0;
      *(float4*)&A[(cob * 8 + col) * 128 + abase + AHI] = v1;
    }
#pragma unroll
    for (int m = 0; m < 64; ++m) y[m] = 0.f;
    if (l < 2) {
#pragma unroll
      for (int m = 0; m < 8; ++m)
        bb[m] = pt[(size_t)(320 + (l + 1) * 4160 + cob * 8 + m) * PLANE];
    }
  };

  // ---- 12 super-iterations of 2 groups; ring half + staging parity STATIC
#pragma unroll 1
  for (int u = 0; u < 12; ++u) {
    const int g0 = u * 2;                // even group: read half 0
    // publish g0+1 -> half 1 (held g0-1, reads done before last barrier)
#pragma unroll
    for (int jj = 0; jj < 4; ++jj) {
      WB[1][sq * 512       + jj * 128 + (sc ^ (jj * 4))] = ((const float*)&paA)[jj];
      WB[1][(2 + sq) * 512 + jj * 128 + (sc ^ (jj * 4))] = ((const float*)&paB)[jj];
    }
    if (g0 + 3 < 24) {                   // refill Pa <- g0+3 (2-group flight)
      const size_t cb = gaddr(g0 + 3);
      paA = *(const float4*)(wb + (cb + tid) * PLANE);
      paB = *(const float4*)(wb + (cb + 256 + tid) * PLANE);
    }
    cgrp(g0, 0);
    asm volatile("s_waitcnt lgkmcnt(0)" ::: "memory");
    __builtin_amdgcn_s_barrier();
    __builtin_amdgcn_sched_barrier(0);

    const int g1 = g0 + 1;               // odd group: read half 1
    if (g1 + 1 < 24) {                   // publish g1+1 -> half 0
#pragma unroll
      for (int jj = 0; jj < 4; ++jj) {
        WB[0][sq * 512       + jj * 128 + (sc ^ (jj * 4))] = ((const float*)&pbA)[jj];
        WB[0][(2 + sq) * 512 + jj * 128 + (sc ^ (jj * 4))] = ((const float*)&pbB)[jj];
      }
    }
    if (g1 + 3 < 24) {                   // refill Pb <- g1+3
      const size_t cb = gaddr(g1 + 3);
      pbA = *(const float4*)(wb + (cb + tid) * PLANE);
      pbB = *(const float4*)(wb + (cb + 256 + tid) * PLANE);
    }
    cgrp(g1, 1);
    asm volatile("s_waitcnt lgkmcnt(0)" ::: "memory");
    __builtin_amdgcn_s_barrier();
    __builtin_amdgcn_sched_barrier(0);
    if ((g1 & 7) == 7) {                 // layer end: flush + extra barrier
      flush(g1 >> 3);
      asm volatile("s_waitcnt lgkmcnt(0)" ::: "memory");
      __builtin_amdgcn_s_barrier();
      __builtin_amdgcn_sched_barrier(0);
    }
  }

  // ---- epilogue: L4 (64 -> 3) + tanh
  float po[24];
#pragma unroll
  for (int m = 0; m < 24; ++m) po[m] = 0.f;
#pragma unroll
  for (int cl = 0; cl < 8; ++cl) {
    const int ci = cob * 8 + cl;
    const float4 a0 = *(const float4*)&A[ci * 128 + abase];
    const float4 a1 = *(const float4*)&A[ci * 128 + abase + AHI];
#pragma unroll
    for (int o = 0; o < 3; ++o) {
      const float w = pt[(size_t)(12803 + ci * 3 + o) * PLANE];
      po[o * 8 + 0] = fmaf(a0.x, w, po[o * 8 + 0]);
      po[o * 8 + 1] = fmaf(a0.y, w, po[o * 8 + 1]);
      po[o * 8 + 2] = fmaf(a0.z, w, po[o * 8 + 2]);
      po[o * 8 + 3] = fmaf(a0.w, w, po[o * 8 + 3]);
      po[o * 8 + 4] = fmaf(a1.x, w, po[o * 8 + 4]);
      po[o * 8 + 5] = fmaf(a1.y, w, po[o * 8 + 5]);
      po[o * 8 + 6] = fmaf(a1.z, w, po[o * 8 + 6]);
      po[o * 8 + 7] = fmaf(a1.w, w, po[o * 8 + 7]);
    }
  }
  asm volatile("s_waitcnt lgkmcnt(0)" ::: "memory");
  __builtin_amdgcn_s_barrier();        // all A reads done -> reuse A
  float* R = A;
#pragma unroll
  for (int m = 0; m < 24; m += 4)
    *(float4*)&R[tid * 28 + m] = *(float4*)&po[m];
  asm volatile("s_waitcnt lgkmcnt(0)" ::: "memory");
  __builtin_amdgcn_s_barrier();
  __builtin_amdgcn_sched_barrier(0);

  if (cob == 0) {                      // tid < 32: one (j, pg) per thread
#pragma unroll
    for (int o = 0; o < 3; ++o) {
      const float bias = pt[(size_t)(12800 + o) * PLANE];
      float s[8];
#pragma unroll
      for (int k = 0; k < 8; ++k) s[k] = bias;
#pragma unroll
      for (int cb = 0; cb < 8; ++cb) {
#pragma unroll
        for (int k = 0; k < 8; ++k)
          s[k] += R[(cb * 32 + tid) * 28 + o * 8 + k];
      }
      float4 v0, v1;
      v0.x = tanhf(s[0]); v0.y = tanhf(s[1]); v0.z = tanhf(s[2]); v0.w = tanhf(s[3]);
      v1.x = tanhf(s[4]); v1.y = tanhf(s[5]); v1.z = tanhf(s[6]); v1.w = tanhf(s[7]);
      float* op = out + (size_t)b * 786432 + (size_t)o * 262144 +
                  (size_t)(i * 8 + pg) * 512 + (size_t)((jg * 4 + j) * 8);
      *(float4*)op = v0;
      *(float4*)(op + 4) = v1;
    }
  }
}

extern "C" void kernel_launch(void* const* d_in, const int* in_sizes, int n_in,
                              void* d_out, int out_size, void* d_ws, size_t ws_size,
                              hipStream_t stream) {
  (void)in_sizes; (void)n_in; (void)d_ws; (void)ws_size; (void)out_size;
  const float* lr = (const float*)d_in[1];  // d_in[0] = highres (unused by the math)
  float* out = (float*)d_out;
  hipLaunchKernelGGL(pqn, dim3(2048), dim3(256), 0, stream, lr, out);
}

// Round 19
// 245.577 us; speedup vs baseline: 1.4843x; 1.0147x over previous
//
#include <hip/hip_runtime.h>
#include <math.h>

// PixelQueryNet v19 = v18 (249us) + explicit per-ci software pipeline in the
// group body (read ci+1 before FMAs of ci) + single staging pair.
// R18 diagnosis: slot = VALU(3424cy) + LDS(3100cy) run SEQUENTIALLY (post-
// barrier read-burst -> FMA-burst; 128-VGPR cap stops the compiler hoisting
// reads into the FMA stream). Pipeline the reads manually; free registers by
// dropping the 2nd gather pair (R16: lookahead-2 == lookahead-1).
//
// Per low-res cell (b,i,j): MLP 4->64->64->64->64->3 (leaky 0.01, tanh) on the
// 64 pixels of its 8x8 tile; weights from lr_params[b,c,i,j] (stride 4096 fl).
// Block = 256 thr = 4 cells(j) x 8 px-rows(pg) x 8 co-blocks(cob); y[8co][8px]
// fp32 in registers. A = two unpadded fp32 k-planes (lane-contiguous b128).
// WB = 16KB ring, 2 halves x 4 tiles, XOR-swizzled rows (conflicts = 0, R18).
// LDS 80KB -> 2 blocks/CU. Grid 2048; siblings n,n+8,n+16,n+24 (same XCD)
// share each 64B weight line -> FETCH ideal. One barrier per group.

static constexpr int PLANE = 4096;
static constexpr int NPAR  = 12995;
static constexpr int AHI   = 8192;  // word offset of k4..7 plane

__device__ __forceinline__ float leaky(float v) { return fmaxf(v, 0.01f * v); }

// PE x-features, compile-time: cos/sin(2*pi*k/8), k = dx.
__device__ __forceinline__ constexpr float cx(int k) {
  constexpr float R = 0.70710678118654752f;
  const float t[8] = {1.f, R, 0.f, -R, -1.f, -R, 0.f, R};
  return t[k];
}
__device__ __forceinline__ constexpr float sx(int k) {
  constexpr float R = 0.70710678118654752f;
  const float t[8] = {0.f, R, 1.f, R, 0.f, -R, -1.f, -R};
  return t[k];
}

__global__ __launch_bounds__(256, 1) void pqn(const float* __restrict__ lr,
                                              float* __restrict__ out) {
  __shared__ alignas(16) float A[2 * AHI];     // 65536 B activations (fp32)
  __shared__ alignas(16) float WB[2][2048];    // 16384 B ring: 2 halves x 4 tiles

  const int tid = threadIdx.x;
  const int j   = tid & 3;
  const int pg  = (tid >> 2) & 7;      // pixel row (dy)
  const int cob = tid >> 5;            // 0..7

  // ---- swizzle: 4 siblings (same XCD) cover one 64B weight line
  const int n  = blockIdx.x;
  const int e2 = (n >> 3) & 3;
  const int P  = (n & 7) | ((n >> 5) << 3);   // 0..511
  const int jg = ((P & 3) << 2) | e2;         // 0..15
  const int i  = (P >> 2) & 63;
  const int b  = (P >> 8) & 1;

  const float* __restrict__ wb =
      lr + (size_t)b * NPAR * PLANE + (size_t)(i * 64 + jg * 4);
  const float* __restrict__ pt = wb + j;      // per-thread channel base

  float fyc, fys;
  sincosf(0.78539816339744830962f * pg, &fys, &fyc);

  const int abase = pg * 16 + j * 4;   // lane-contiguous A offset
  const int swz   = j * 4;             // weight-row XOR swizzle
  const int sq    = tid >> 7;          // staging: which tile-pair half
  const int sc    = tid & 127;         // staging channel within tile

  auto gaddr = [&](int g) -> size_t {  // first channel of group g's weights
    return 384 + (size_t)(g >> 3) * 4160 + (size_t)(g & 7) * 512;
  };

  float4 paA, paB;                     // single staging pair (1-group flight)
  {
    const size_t cb = gaddr(0);
    paA = *(const float4*)(wb + (cb + tid) * PLANE);
    paB = *(const float4*)(wb + (cb + 256 + tid) * PLANE);
  }
  float l0b[8], l0w[32], bb[8];
#pragma unroll
  for (int m = 0; m < 8; ++m) l0b[m] = pt[(size_t)(cob * 8 + m) * PLANE];
#pragma unroll
  for (int f = 0; f < 4; ++f)
#pragma unroll
    for (int m = 0; m < 8; ++m)
      l0w[f * 8 + m] = pt[(size_t)(64 + f * 64 + cob * 8 + m) * PLANE];
#pragma unroll
  for (int m = 0; m < 8; ++m) bb[m] = pt[(size_t)(320 + cob * 8 + m) * PLANE];

  // ---- L0 compute -> A
#pragma unroll
  for (int col = 0; col < 8; ++col) {
    float t[8];
#pragma unroll
    for (int k = 0; k < 8; ++k) {
      float v = l0b[col];
      v = fmaf(cx(k), l0w[col], v);
      v = fmaf(sx(k), l0w[8 + col], v);
      v = fmaf(fyc,  l0w[16 + col], v);
      v = fmaf(fys,  l0w[24 + col], v);
      t[k] = leaky(v);
    }
    float4 v0, v1;
    v0.x = t[0]; v0.y = t[1]; v0.z = t[2]; v0.w = t[3];
    v1.x = t[4]; v1.y = t[5]; v1.z = t[6]; v1.w = t[7];
    *(float4*)&A[(cob * 8 + col) * 128 + abase]       = v0;
    *(float4*)&A[(cob * 8 + col) * 128 + abase + AHI] = v1;
  }
  // publish group 0 -> half 0; refill Pa <- g1
#pragma unroll
  for (int jj = 0; jj < 4; ++jj) {
    WB[0][sq * 512       + jj * 128 + (sc ^ (jj * 4))] = ((const float*)&paA)[jj];
    WB[0][(2 + sq) * 512 + jj * 128 + (sc ^ (jj * 4))] = ((const float*)&paB)[jj];
  }
  {
    const size_t cb = gaddr(1);
    paA = *(const float4*)(wb + (cb + tid) * PLANE);
    paB = *(const float4*)(wb + (cb + 256 + tid) * PLANE);
  }
  asm volatile("s_waitcnt lgkmcnt(0)" ::: "memory");
  __builtin_amdgcn_s_barrier();
  __builtin_amdgcn_sched_barrier(0);

  float y[64];
#pragma unroll
  for (int m = 0; m < 64; ++m) y[m] = 0.f;

  // one group's 4 tiles from ring half h: per-ci software pipeline
  auto cgrp = [&](int g, int h) {
    const float* WH = WB[h];
    const int r0 = (g & 7) * 8;
    // prime ci = r0 (t=0: q=0, cl=0)
    float4 a0 = *(const float4*)&A[r0 * 128 + abase];
    float4 a1 = *(const float4*)&A[r0 * 128 + abase + AHI];
    float4 w0 = *(const float4*)&WH[j * 128 + ((cob * 8) ^ swz)];
    float4 w1 = *(const float4*)&WH[j * 128 + ((cob * 8 + 4) ^ swz)];
#pragma unroll
    for (int t = 0; t < 8; ++t) {
      float4 na0, na1, nw0, nw1;
      if (t < 7) {                       // issue ci+1's reads BEFORE FMAs
        const int tn = t + 1;
        const int ci = r0 + tn;
        const int q = tn >> 1, cl = tn & 1;
        na0 = *(const float4*)&A[ci * 128 + abase];
        na1 = *(const float4*)&A[ci * 128 + abase + AHI];
        nw0 = *(const float4*)&WH[q * 512 + j * 128 + ((cl * 64 + cob * 8) ^ swz)];
        nw1 = *(const float4*)&WH[q * 512 + j * 128 + ((cl * 64 + cob * 8 + 4) ^ swz)];
      }
      const float av[8] = {a0.x, a0.y, a0.z, a0.w, a1.x, a1.y, a1.z, a1.w};
      const float wv[8] = {w0.x, w0.y, w0.z, w0.w, w1.x, w1.y, w1.z, w1.w};
#pragma unroll
      for (int col = 0; col < 8; ++col)
#pragma unroll
        for (int k = 0; k < 8; ++k)
          y[col * 8 + k] = fmaf(av[k], wv[col], y[col * 8 + k]);
      if (t < 7) { a0 = na0; a1 = na1; w0 = nw0; w1 = nw1; }
    }
  };
  auto flush = [&](int l) {              // layer end: bias + leaky -> A
#pragma unroll
    for (int col = 0; col < 8; ++col) {
      float4 v0, v1;
      v0.x = leaky(y[col * 8 + 0] + bb[col]);
      v0.y = leaky(y[col * 8 + 1] + bb[col]);
      v0.z = leaky(y[col * 8 + 2] + bb[col]);
      v0.w = leaky(y[col * 8 + 3] + bb[col]);
      v1.x = leaky(y[col * 8 + 4] + bb[col]);
      v1.y = leaky(y[col * 8 + 5] + bb[col]);
      v1.z = leaky(y[col * 8 + 6] + bb[col]);
      v1.w = leaky(y[col * 8 + 7] + bb[col]);
      *(float4*)&A[(cob * 8 + col) * 128 + abase]       = v0;
      *(float4*)&A[(cob * 8 + col) * 128 + abase + AHI] = v1;
    }
#pragma unroll
    for (int m = 0; m < 64; ++m) y[m] = 0.f;
    if (l < 2) {
#pragma unroll
      for (int m = 0; m < 8; ++m)
        bb[m] = pt[(size_t)(320 + (l + 1) * 4160 + cob * 8 + m) * PLANE];
    }
  };

  // ---- 12 super-iterations of 2 groups; ring half STATIC per position
#pragma unroll 1
  for (int u = 0; u < 12; ++u) {
    const int g0 = u * 2;                // even group: read half 0
#pragma unroll
    for (int jj = 0; jj < 4; ++jj) {     // publish g0+1 -> half 1 (from Pa)
      WB[1][sq * 512       + jj * 128 + (sc ^ (jj * 4))] = ((const float*)&paA)[jj];
      WB[1][(2 + sq) * 512 + jj * 128 + (sc ^ (jj * 4))] = ((const float*)&paB)[jj];
    }
    if (g0 + 2 < 24) {                   // refill Pa <- g0+2
      const size_t cb = gaddr(g0 + 2);
      paA = *(const float4*)(wb + (cb + tid) * PLANE);
      paB = *(const float4*)(wb + (cb + 256 + tid) * PLANE);
    }
    cgrp(g0, 0);
    asm volatile("s_waitcnt lgkmcnt(0)" ::: "memory");
    __builtin_amdgcn_s_barrier();
    __builtin_amdgcn_sched_barrier(0);

    const int g1 = g0 + 1;               // odd group: read half 1
    if (g1 + 1 < 24) {                   // publish g1+1 -> half 0 (from Pa)
#pragma unroll
      for (int jj = 0; jj < 4; ++jj) {
        WB[0][sq * 512       + jj * 128 + (sc ^ (jj * 4))] = ((const float*)&paA)[jj];
        WB[0][(2 + sq) * 512 + jj * 128 + (sc ^ (jj * 4))] = ((const float*)&paB)[jj];
      }
    }
    if (g1 + 2 < 24) {                   // refill Pa <- g1+2
      const size_t cb = gaddr(g1 + 2);
      paA = *(const float4*)(wb + (cb + tid) * PLANE);
      paB = *(const float4*)(wb + (cb + 256 + tid) * PLANE);
    }
    cgrp(g1, 1);
    asm volatile("s_waitcnt lgkmcnt(0)" ::: "memory");
    __builtin_amdgcn_s_barrier();
    __builtin_amdgcn_sched_barrier(0);
    if ((g1 & 7) == 7) {                 // layer end: flush + extra barrier
      flush(g1 >> 3);
      asm volatile("s_waitcnt lgkmcnt(0)" ::: "memory");
      __builtin_amdgcn_s_barrier();
      __builtin_amdgcn_sched_barrier(0);
    }
  }

  // ---- epilogue: L4 (64 -> 3) + tanh
  float po[24];
#pragma unroll
  for (int m = 0; m < 24; ++m) po[m] = 0.f;
#pragma unroll
  for (int cl = 0; cl < 8; ++cl) {
    const int ci = cob * 8 + cl;
    const float4 a0 = *(const float4*)&A[ci * 128 + abase];
    const float4 a1 = *(const float4*)&A[ci * 128 + abase + AHI];
#pragma unroll
    for (int o = 0; o < 3; ++o) {
      const float w = pt[(size_t)(12803 + ci * 3 + o) * PLANE];
      po[o * 8 + 0] = fmaf(a0.x, w, po[o * 8 + 0]);
      po[o * 8 + 1] = fmaf(a0.y, w, po[o * 8 + 1]);
      po[o * 8 + 2] = fmaf(a0.z, w, po[o * 8 + 2]);
      po[o * 8 + 3] = fmaf(a0.w, w, po[o * 8 + 3]);
      po[o * 8 + 4] = fmaf(a1.x, w, po[o * 8 + 4]);
      po[o * 8 + 5] = fmaf(a1.y, w, po[o * 8 + 5]);
      po[o * 8 + 6] = fmaf(a1.z, w, po[o * 8 + 6]);
      po[o * 8 + 7] = fmaf(a1.w, w, po[o * 8 + 7]);
    }
  }
  asm volatile("s_waitcnt lgkmcnt(0)" ::: "memory");
  __builtin_amdgcn_s_barrier();        // all A reads done -> reuse A
  float* R = A;
#pragma unroll
  for (int m = 0; m < 24; m += 4)
    *(float4*)&R[tid * 28 + m] = *(float4*)&po[m];
  asm volatile("s_waitcnt lgkmcnt(0)" ::: "memory");
  __builtin_amdgcn_s_barrier();
  __builtin_amdgcn_sched_barrier(0);

  if (cob == 0) {                      // tid < 32: one (j, pg) per thread
#pragma unroll
    for (int o = 0; o < 3; ++o) {
      const float bias = pt[(size_t)(12800 + o) * PLANE];
      float s[8];
#pragma unroll
      for (int k = 0; k < 8; ++k) s[k] = bias;
#pragma unroll
      for (int cb = 0; cb < 8; ++cb) {
#pragma unroll
        for (int k = 0; k < 8; ++k)
          s[k] += R[(cb * 32 + tid) * 28 + o * 8 + k];
      }
      float4 v0, v1;
      v0.x = tanhf(s[0]); v0.y = tanhf(s[1]); v0.z = tanhf(s[2]); v0.w = tanhf(s[3]);
      v1.x = tanhf(s[4]); v1.y = tanhf(s[5]); v1.z = tanhf(s[6]); v1.w = tanhf(s[7]);
      float* op = out + (size_t)b * 786432 + (size_t)o * 262144 +
                  (size_t)(i * 8 + pg) * 512 + (size_t)((jg * 4 + j) * 8);
      *(float4*)op = v0;
      *(float4*)(op + 4) = v1;
    }
  }
}

extern "C" void kernel_launch(void* const* d_in, const int* in_sizes, int n_in,
                              void* d_out, int out_size, void* d_ws, size_t ws_size,
                              hipStream_t stream) {
  (void)in_sizes; (void)n_in; (void)d_ws; (void)ws_size; (void)out_size;
  const float* lr = (const float*)d_in[1];  // d_in[0] = highres (unused by the math)
  float* out = (float*)d_out;
  hipLaunchKernelGGL(pqn, dim3(2048), dim3(256), 0, stream, lr, out);
}